// Round 5
// baseline (343.394 us; speedup 1.0000x reference)
//
#include <hip/hip_runtime.h>

// DNAMite GAM on MI355X. Round 7b: barrier-free wave-independent rewrite
// (round-7 resubmit; fixed cvt_pkrtz return type: __fp16x2, not _Float16x2).
// Round 6 was stall-bound (~90% idle): 2 barriers/tile x 8 tiles coupled all
// 4 waves to every wave's gather latency, with only ~2-3 blocks/CU of TLP.
// Now: 32x32x16 MFMA A-frags (32 rows / 4 VGPR) let ONE wave own the full
// 128-hidden slice for 32 batch cols. W0/W1 staged once to LDS (f16, [h][k],
// XOR-swizzled; read-only after ONE __syncthreads). H1 stays in registers:
// D->B transpose via cvt_pkrtz pack + shfl_xor(32) half-swap. Layer-2 dot is
// wave-local. ZERO barriers in the main loop; 4 independent iterations/wave.

typedef _Float16 f16x8 __attribute__((ext_vector_type(8)));
typedef __fp16 fp16x2 __attribute__((ext_vector_type(2)));
typedef float f32x4 __attribute__((ext_vector_type(4)));
typedef float f32x16 __attribute__((ext_vector_type(16)));

constexpr int Bsz = 512;
constexpr int NF  = 64;
constexpr int NE  = 32;
constexpr int NH  = 128;
constexpr int NP  = 2016;
constexpr int NG  = NP + NF;       // 2080 groups = grid
constexpr int NITER = 4;           // 4 iters x (4 waves x 32 cols) = 512
constexpr int NSEG = 8, GSEG = NG / NSEG;  // 260

// ws layout (floats): [NG*Bsz] partials | [NSEG*Bsz] stage2 | pairsT ints
constexpr size_t WS_S2 = (size_t)NG * Bsz;
constexpr size_t WS_PT = WS_S2 + (size_t)NSEG * Bsz;

__device__ __forceinline__ float smoothz(float z) {
  float s = fmaf(-2.0f * z * z, z, fmaf(1.5f, z, 0.5f));
  if (z <= -0.5f) s = 0.0f;
  if (z >=  0.5f) s = 1.0f;
  return s;
}

// [512][4032] -> [4032][512] int transpose, LDS-tiled 32x32.
__global__ void transpose_pairs_kernel(const int* __restrict__ pairs,
                                       int* __restrict__ pt) {
  __shared__ int tile[32][33];
  const int bt = blockIdx.x;
  const int qt = blockIdx.y;
  const int t  = threadIdx.x;
  const int tq = t & 7, tb = t >> 3;
  const int brow  = bt * 32 + tb;
  const int qbase = qt * 32 + tq * 4;
#pragma unroll
  for (int j = 0; j < 4; ++j)
    tile[tb][tq * 4 + j] = pairs[brow * (2 * NP) + qbase + j];
  __syncthreads();
  const int ob = t & 7, oq = t >> 3;
  const int qrow = qt * 32 + oq;
#pragma unroll
  for (int j = 0; j < 4; ++j)
    pt[(size_t)qrow * Bsz + bt * 32 + ob * 4 + j] = tile[ob * 4 + j][oq];
}

__global__ __launch_bounds__(256, 3) void fused_groups_kernel(
    const int* __restrict__ mains, const int* __restrict__ pt,
    const float* __restrict__ emb,
    const float* __restrict__ mw0, const float* __restrict__ mw1,
    const float* __restrict__ mw2, const float* __restrict__ mb0,
    const float* __restrict__ mb1, const float* __restrict__ mb2,
    const float* __restrict__ z_main,
    const float* __restrict__ pw0, const float* __restrict__ pw1,
    const float* __restrict__ pw2, const float* __restrict__ pb0,
    const float* __restrict__ pb1, const float* __restrict__ pb2,
    const float* __restrict__ z_pairs,
    const int* __restrict__ pairs_list, const int* __restrict__ foff,
    float* __restrict__ ws) {
  // Weights in LDS as W^T: [h-row][k], f16, 16B blocks XOR-swizzled by row.
  __shared__ _Float16 sW1[NH * NH];             // 32 KB
  __shared__ _Float16 sW0[NH * 64];             // 16 KB (mains use k<32)
  __shared__ __align__(16) float sBias[3 * NH]; // b0 | b1 | w2

  const int t    = threadIdx.x;
  const int wave = t >> 6;
  const int lane = t & 63;
  const int r    = lane & 31;   // MFMA A-row / C-col / batch col within wave
  const int hd   = lane >> 5;   // k-half selector
  const int g    = blockIdx.x;
  const bool is_pair = (g < NP);

  const float *W0, *W1, *w2p, *bv0, *bv1;
  float b2s, z;
  int off0 = 0, off1 = 0, fid = 0;
  if (is_pair) {
    W0  = pw0 + (size_t)g * (2 * NE * NH);
    W1  = pw1 + (size_t)g * (NH * NH);
    w2p = pw2 + (size_t)g * NH;
    bv0 = pb0 + (size_t)g * NH;
    bv1 = pb1 + (size_t)g * NH;
    b2s = pb2[g];
    z   = smoothz(z_pairs[g]);
    off0 = foff[pairs_list[2 * g + 0]];
    off1 = foff[pairs_list[2 * g + 1]];
  } else {
    fid = g - NP;
    W0  = mw0 + (size_t)fid * (NE * NH);
    W1  = mw1 + (size_t)fid * (NH * NH);
    w2p = mw2 + (size_t)fid * NH;
    bv0 = mb0 + (size_t)fid * NH;
    bv1 = mb1 + (size_t)fid * NH;
    b2s = mb2[fid];
    z   = smoothz(z_main[fid]);
    off0 = foff[fid];
  }

  // ---- stage W1^T -> sW1 (coalesced dword reads, f16x8 swizzled stores) ----
#pragma unroll
  for (int i = 0; i < 8; ++i) {
    const int f = t + i * 256, h = f & 127, kb = f >> 7;   // kb 0..15
    f16x8 v;
#pragma unroll
    for (int j = 0; j < 8; ++j)
      v[j] = (_Float16)W1[(size_t)(kb * 8 + j) * NH + h];
    *(f16x8*)&sW1[h * NH + ((kb ^ (h & 7)) * 8)] = v;
  }
  // ---- stage W0^T -> sW0 ----
  if (is_pair) {
#pragma unroll
    for (int i = 0; i < 4; ++i) {
      const int f = t + i * 256, h = f & 127, kb = f >> 7; // kb 0..7
      f16x8 v;
#pragma unroll
      for (int j = 0; j < 8; ++j)
        v[j] = (_Float16)W0[(size_t)(kb * 8 + j) * NH + h];
      *(f16x8*)&sW0[h * 64 + ((kb ^ (h & 7)) * 8)] = v;
    }
  } else {
#pragma unroll
    for (int i = 0; i < 2; ++i) {
      const int f = t + i * 256, h = f & 127, kb = f >> 7; // kb 0..3
      f16x8 v;
#pragma unroll
      for (int j = 0; j < 8; ++j)
        v[j] = (_Float16)W0[(size_t)(kb * 8 + j) * NH + h];
      *(f16x8*)&sW0[h * 64 + ((kb ^ (h & 7)) * 8)] = v;
    }
  }
  // ---- biases / w2 ----
  if (t < 96) {
    const int which = t >> 5;                    // 0:b0 1:b1 2:w2
    const int i = (t & 31) * 4;
    const float* src = which == 0 ? bv0 : (which == 1 ? bv1 : w2p);
    *(float4*)&sBias[which * NH + i] = *(const float4*)(src + i);
  }

  // ---- preload all bin indices for this lane's 4 columns ----
  int idxA[NITER], idxB[NITER];
#pragma unroll
  for (int i = 0; i < NITER; ++i) {
    const int col = i * 128 + wave * 32 + r;
    if (is_pair) {
      idxA[i] = pt[(size_t)(2 * g + 0) * Bsz + col] + off0;
      idxB[i] = pt[(size_t)(2 * g + 1) * Bsz + col] + off1;
    } else {
      idxA[i] = mains[col * NF + fid] + off0;
    }
  }

  // per-lane embedding registers: er[2k],er[2k+1] = 8 floats of k-chunk k
  float4 er[8];
  auto ldemb = [&](int i) {
    const float* e0 = emb + (size_t)idxA[i] * NE + hd * 8;
    er[0] = ((const float4*)e0)[0];
    er[1] = ((const float4*)e0)[1];
    er[2] = ((const float4*)(e0 + 16))[0];
    er[3] = ((const float4*)(e0 + 16))[1];
    if (is_pair) {
      const float* e1 = emb + (size_t)idxB[i] * NE + hd * 8;
      er[4] = ((const float4*)e1)[0];
      er[5] = ((const float4*)e1)[1];
      er[6] = ((const float4*)(e1 + 16))[0];
      er[7] = ((const float4*)(e1 + 16))[1];
    }
  };

  ldemb(0);
  __syncthreads();  // the ONLY barrier: sW0/sW1/sBias read-only hereafter

#pragma unroll
  for (int iter = 0; iter < NITER; ++iter) {
    // ---- acc init with b0 (broadcast b128 reads; row = 8q + 4hd + i) ----
    f32x16 acc[4];
#pragma unroll
    for (int m = 0; m < 4; ++m)
#pragma unroll
      for (int q = 0; q < 4; ++q) {
        const f32x4 b = *(const f32x4*)&sBias[m * 32 + q * 8 + 4 * hd];
        acc[m][4 * q + 0] = b[0]; acc[m][4 * q + 1] = b[1];
        acc[m][4 * q + 2] = b[2]; acc[m][4 * q + 3] = b[3];
      }

    // ---- GEMM0: acc[m] += W0^T(m-rows) x E^T; B built from er in-place ----
#pragma unroll
    for (int kc = 0; kc < 4; ++kc) {
      if (kc < 2 || is_pair) {
        f16x8 bf;
        bf[0] = (_Float16)er[2 * kc].x; bf[1] = (_Float16)er[2 * kc].y;
        bf[2] = (_Float16)er[2 * kc].z; bf[3] = (_Float16)er[2 * kc].w;
        bf[4] = (_Float16)er[2 * kc + 1].x; bf[5] = (_Float16)er[2 * kc + 1].y;
        bf[6] = (_Float16)er[2 * kc + 1].z; bf[7] = (_Float16)er[2 * kc + 1].w;
#pragma unroll
        for (int m = 0; m < 4; ++m) {
          const f16x8 a = *(const f16x8*)
              &sW0[(m * 32 + r) * 64 + (((2 * kc + hd) ^ (r & 7)) * 8)];
          acc[m] = __builtin_amdgcn_mfma_f32_32x32x16_f16(a, bf, acc[m], 0, 0, 0);
        }
      }
    }

    // issue next iteration's embedding gather (covered by pack+GEMM1+dot)
    if (iter + 1 < NITER) ldemb(iter + 1);

    // ---- in-register transpose: H1 = relu(acc) -> GEMM1 B-frags hb[8] ----
    // D elem e of acc[a] is row (e&3)+8*(e>>2)+4*hd; pack pairs -> f16x2 in a
    // float, swap halves with shfl_xor(32), assemble per dest-half.
    f16x8 hb[8];
#pragma unroll
    for (int a2 = 0; a2 < 4; ++a2) {
      float D[8], Q[8];
#pragma unroll
      for (int p = 0; p < 8; ++p) {
        const float lo = fmaxf(acc[a2][2 * p], 0.0f);
        const float hi = fmaxf(acc[a2][2 * p + 1], 0.0f);
        const fp16x2 pk = __builtin_amdgcn_cvt_pkrtz(lo, hi);
        D[p] = __builtin_bit_cast(float, pk);
        Q[p] = __shfl_xor(D[p], 32, 64);
      }
#pragma unroll
      for (int b = 0; b < 2; ++b) {
        f32x4 w;
        if (hd == 0) {
          w[0] = D[4 * b + 0]; w[1] = D[4 * b + 1];
          w[2] = Q[4 * b + 0]; w[3] = Q[4 * b + 1];
        } else {
          w[0] = Q[4 * b + 2]; w[1] = Q[4 * b + 3];
          w[2] = D[4 * b + 2]; w[3] = D[4 * b + 3];
        }
        hb[2 * a2 + b] = __builtin_bit_cast(f16x8, w);
      }
    }

    // ---- acc re-init with b1 ----
#pragma unroll
    for (int m = 0; m < 4; ++m)
#pragma unroll
      for (int q = 0; q < 4; ++q) {
        const f32x4 b = *(const f32x4*)&sBias[NH + m * 32 + q * 8 + 4 * hd];
        acc[m][4 * q + 0] = b[0]; acc[m][4 * q + 1] = b[1];
        acc[m][4 * q + 2] = b[2]; acc[m][4 * q + 3] = b[3];
      }

    // ---- GEMM1: acc[m] += W1^T(m-rows) x H1 ----
#pragma unroll
    for (int kc = 0; kc < 8; ++kc)
#pragma unroll
      for (int m = 0; m < 4; ++m) {
        const f16x8 a = *(const f16x8*)
            &sW1[(m * 32 + r) * NH + (((2 * kc + hd) ^ (r & 7)) * 8)];
        acc[m] = __builtin_amdgcn_mfma_f32_32x32x16_f16(a, hb[kc], acc[m], 0, 0, 0);
      }

    // ---- layer 2: per-lane dot over 64 elems + half-swap reduce ----
    float y = 0.0f;
#pragma unroll
    for (int m = 0; m < 4; ++m)
#pragma unroll
      for (int q = 0; q < 4; ++q) {
        const f32x4 w2q = *(const f32x4*)&sBias[2 * NH + m * 32 + q * 8 + 4 * hd];
#pragma unroll
        for (int i2 = 0; i2 < 4; ++i2)
          y = fmaf(fmaxf(acc[m][4 * q + i2], 0.0f), w2q[i2], y);
      }
    y += __shfl_xor(y, 32, 64);
    if (lane < 32) {
      const int col = iter * 128 + wave * 32 + r;
      ws[(size_t)g * Bsz + col] = (y + b2s) * z;
    }
  }
}

__global__ void reduce1_kernel(const float* __restrict__ part,
                               float* __restrict__ s2) {
  const int b   = blockIdx.x * 256 + threadIdx.x;
  const int seg = blockIdx.y;
  float s = 0.0f;
#pragma unroll 8
  for (int g = seg * GSEG; g < (seg + 1) * GSEG; ++g)
    s += part[(size_t)g * Bsz + b];
  s2[seg * Bsz + b] = s;
}

__global__ void reduce2_kernel(const float* __restrict__ s2,
                               float* __restrict__ out) {
  const int b = blockIdx.x * 256 + threadIdx.x;
  float s = 0.0f;
#pragma unroll
  for (int k = 0; k < NSEG; ++k) s += s2[k * Bsz + b];
  out[b] = s;
}

extern "C" void kernel_launch(void* const* d_in, const int* in_sizes, int n_in,
                              void* d_out, int out_size, void* d_ws,
                              size_t ws_size, hipStream_t stream) {
  const int*   mains      = (const int*)d_in[0];
  const int*   pairs      = (const int*)d_in[1];
  const float* emb        = (const float*)d_in[2];
  const float* mw0        = (const float*)d_in[3];
  const float* mw1        = (const float*)d_in[4];
  const float* mw2        = (const float*)d_in[5];
  const float* mb0        = (const float*)d_in[6];
  const float* mb1        = (const float*)d_in[7];
  const float* mb2        = (const float*)d_in[8];
  const float* z_main     = (const float*)d_in[9];
  const float* pw0        = (const float*)d_in[10];
  const float* pw1        = (const float*)d_in[11];
  const float* pw2        = (const float*)d_in[12];
  const float* pb0        = (const float*)d_in[13];
  const float* pb1        = (const float*)d_in[14];
  const float* pb2        = (const float*)d_in[15];
  const float* z_pairs    = (const float*)d_in[16];
  const int*   pairs_list = (const int*)d_in[17];
  const int*   foff       = (const int*)d_in[18];
  float* ws   = (float*)d_ws;
  float* out  = (float*)d_out;
  float* part = ws;
  float* s2   = ws + WS_S2;
  int*   pt   = (int*)(ws + WS_PT);

  transpose_pairs_kernel<<<dim3(16, 126), 256, 0, stream>>>(pairs, pt);
  fused_groups_kernel<<<NG, 256, 0, stream>>>(
      mains, pt, emb, mw0, mw1, mw2, mb0, mb1, mb2, z_main, pw0, pw1, pw2,
      pb0, pb1, pb2, z_pairs, pairs_list, foff, part);
  reduce1_kernel<<<dim3(2, NSEG), 256, 0, stream>>>(part, s2);
  reduce2_kernel<<<2, 256, 0, stream>>>(s2, out);
}